// Round 4
// baseline (1710.227 us; speedup 1.0000x reference)
//
#include <hip/hip_runtime.h>
#include <hip/hip_bf16.h>
#include <stdint.h>

// SAGE (GraphSAGE, LSTM aggregator). f32 I/O, bf16 MFMA internally.
// N=30000, DMAX=16, dims 128 -> 256 -> 64.
// R10 -> R11 (R10 FAILED: nt-loads no-op, FETCH unchanged. Real signal:
// NOTHING saturated -- occupancy 16.6%, hbm 20%, VALU 22%. Degree-sort made
// 469 blocks of wildly different length, all co-resident (512 slots @
// 2 blk/CU) -> no backfill queue; machine drains while ~29 deg-16 blocks
// grind 16 steps on half-CUs. Bytes fell 2.3x but time only 1.4x = tail):
//   1. 1024-thread blocks (16 waves = 2 row-waves x 8 col-waves) on the
//      same 64-node tile -> 1 block/CU. 469 blocks > 256 CUs: real queue,
//      finished CUs backfill; tail blocks get a FULL CU (2x per-step MFMA
//      throughput).
//   2. DESCENDING degree sort = LPT scheduling: heavy blocks start first,
//      light blocks fill the drain. work/CU ~15.6 steps ~= deg-16 chain.
//   3. Software-pipelined xg gather: refill u[ct] for t+1 right after
//      pointwise consumes it (same regs, in flight across the barrier,
//      hidden behind next step's MFMA). nt-load reverted.
// Verified layouts (learn_hip m89/m91): A[m=lane&15][k=q*8+j],
// D[row=q*4+r][col=lane&15]; W[4F,F] row-major == gemm-BT B-frag layout.

#define NN 30000
#define DMAXX 16

typedef __bf16 bf16_t;
typedef __bf16 bf16x8 __attribute__((ext_vector_type(8)));
typedef float f32x4 __attribute__((ext_vector_type(4)));
typedef unsigned short u16x4 __attribute__((ext_vector_type(4)));

// persistent scratch (fully rewritten every call; no cross-call state reuse)
__device__ __align__(16) bf16_t g_hbuf[(size_t)NN * 256];    // layer-1 output h1
__device__ __align__(16) bf16_t g_xg1[(size_t)NN * 512];     // feat@Wih1^T + biases
__device__ __align__(16) bf16_t g_xg2[(size_t)NN * 1024];    // h1@Wih2^T + biases
__device__ __align__(16) bf16_t g_wbuf[753664];              // bf16 weight copies
__device__ int g_perm[NN];                                   // degree-sorted node ids

#define OFF_WIH1 0
#define OFF_WHH1 65536
#define OFF_WSELF1 131072
#define OFF_WNEIGH1 163840
#define OFF_WIH2 196608
#define OFF_WHH2 458752
#define OFF_WSELF2 720896
#define OFF_WNEIGH2 737280
#define W_TOTAL 753664

__global__ __launch_bounds__(256)
void cvt_weights(const float* __restrict__ s0, const float* __restrict__ s1,
                 const float* __restrict__ s2, const float* __restrict__ s3,
                 const float* __restrict__ s4, const float* __restrict__ s5,
                 const float* __restrict__ s6, const float* __restrict__ s7)
{
    int i = (blockIdx.x * 256 + threadIdx.x) * 4;
    if (i >= W_TOTAL) return;
    const float* src; int off;
    if      (i < OFF_WHH1)   { src = s0; off = OFF_WIH1; }
    else if (i < OFF_WSELF1) { src = s1; off = OFF_WHH1; }
    else if (i < OFF_WNEIGH1){ src = s2; off = OFF_WSELF1; }
    else if (i < OFF_WIH2)   { src = s3; off = OFF_WNEIGH1; }
    else if (i < OFF_WHH2)   { src = s4; off = OFF_WIH2; }
    else if (i < OFF_WSELF2) { src = s5; off = OFF_WHH2; }
    else if (i < OFF_WNEIGH2){ src = s6; off = OFF_WSELF2; }
    else                     { src = s7; off = OFF_WNEIGH2; }
    float4 v = *reinterpret_cast<const float4*>(src + (i - off));
    bf16_t o[4] __attribute__((aligned(8)));
    o[0] = (bf16_t)v.x; o[1] = (bf16_t)v.y; o[2] = (bf16_t)v.z; o[3] = (bf16_t)v.w;
    *reinterpret_cast<uint2*>(&g_wbuf[i]) = *reinterpret_cast<const uint2*>(o);
}

// counting sort of node ids by DESCENDING degree (LPT block scheduling).
// Non-stable (atomic slot grab) -- per-node results are independent of
// grouping, so any permutation is correct.
__global__ __launch_bounds__(256)
void build_perm(const int* __restrict__ deg, int* __restrict__ perm)
{
    __shared__ int s_base[DMAXX + 1];
    const int tid = threadIdx.x;
    if (tid <= DMAXX) s_base[tid] = 0;
    __syncthreads();
    for (int i = tid; i < NN; i += 256) {
        int d = deg[i]; d = d < 0 ? 0 : (d > DMAXX ? DMAXX : d);
        atomicAdd(&s_base[d], 1);
    }
    __syncthreads();
    if (tid == 0) {
        int acc = 0;
        for (int d = DMAXX; d >= 0; --d) { int c = s_base[d]; s_base[d] = acc; acc += c; }
    }
    __syncthreads();
    for (int i = tid; i < NN; i += 256) {
        int d = deg[i]; d = d < 0 ? 0 : (d > DMAXX ? DMAXX : d);
        int p = atomicAdd(&s_base[d], 1);
        perm[p] = i;
    }
}

__device__ __forceinline__ float fsig(float x) { return 1.0f / (1.0f + __expf(-x)); }
__device__ __forceinline__ float ftanh(float x) { return 1.0f - 2.0f / (__expf(2.0f * x) + 1.0f); }
__device__ __forceinline__ float bf2f(unsigned short s) {
    union { unsigned u; float f; } v; v.u = ((unsigned)s) << 16; return v.f;
}

// stage a 64-row x-tile (linear rows, row-clamped) into LDS as bf16
template<int F, int LDA, int NT, bool XF32>
__device__ __forceinline__ void stage_tile(bf16_t* dst, const void* src, int row0, int tid)
{
    constexpr int UN = F / 8;          // 16B(bf16) units per row
    for (int e = tid; e < 64 * UN; e += NT) {
        int m = e / UN, sub = e - m * UN;
        int row = row0 + m; if (row >= NN) row = NN - 1;
        if constexpr (XF32) {
            const float* p = (const float*)src + (size_t)row * F + sub * 8;
            float4 f0 = reinterpret_cast<const float4*>(p)[0];
            float4 f1 = reinterpret_cast<const float4*>(p)[1];
            bf16_t t[8] __attribute__((aligned(16)));
            t[0]=(bf16_t)f0.x; t[1]=(bf16_t)f0.y; t[2]=(bf16_t)f0.z; t[3]=(bf16_t)f0.w;
            t[4]=(bf16_t)f1.x; t[5]=(bf16_t)f1.y; t[6]=(bf16_t)f1.z; t[7]=(bf16_t)f1.w;
            *reinterpret_cast<uint4*>(&dst[m * LDA + sub * 8]) = *reinterpret_cast<const uint4*>(t);
        } else {
            const bf16_t* p = (const bf16_t*)src + (size_t)row * F + sub * 8;
            *reinterpret_cast<uint4*>(&dst[m * LDA + sub * 8]) = *reinterpret_cast<const uint4*>(p);
        }
    }
}

// stage a 64-row x-tile with per-row node ids (from LDS array) into LDS
template<int F, int LDA, int NT, bool XF32>
__device__ __forceinline__ void stage_rows(bf16_t* dst, const void* src, const int* nodes, int tid)
{
    constexpr int UN = F / 8;
    for (int e = tid; e < 64 * UN; e += NT) {
        int m = e / UN, sub = e - m * UN;
        int row = nodes[m];
        if constexpr (XF32) {
            const float* p = (const float*)src + (size_t)row * F + sub * 8;
            float4 f0 = reinterpret_cast<const float4*>(p)[0];
            float4 f1 = reinterpret_cast<const float4*>(p)[1];
            bf16_t t[8] __attribute__((aligned(16)));
            t[0]=(bf16_t)f0.x; t[1]=(bf16_t)f0.y; t[2]=(bf16_t)f0.z; t[3]=(bf16_t)f0.w;
            t[4]=(bf16_t)f1.x; t[5]=(bf16_t)f1.y; t[6]=(bf16_t)f1.z; t[7]=(bf16_t)f1.w;
            *reinterpret_cast<uint4*>(&dst[m * LDA + sub * 8]) = *reinterpret_cast<const uint4*>(t);
        } else {
            const bf16_t* p = (const bf16_t*)src + (size_t)row * F + sub * 8;
            *reinterpret_cast<uint4*>(&dst[m * LDA + sub * 8]) = *reinterpret_cast<const uint4*>(p);
        }
    }
}

// xg[N, 4F] (gate-interleaved [c][g]) = x[N,F] @ W[4F,F]^T + b0 + b1
template<int F, int G, int NW, bool XF32>
__global__ __launch_bounds__(NW * 64, 2)
void xg_gemm(const void* __restrict__ xsrc_v, const bf16_t* __restrict__ W,
             const float* __restrict__ b0, const float* __restrict__ b1v,
             bf16_t* __restrict__ xg)
{
    constexpr int LDA = F + 8, KK = F / 32, NT = NW * 64;
    constexpr int CPW = G / NW;        // linear out-cols per wave
    constexpr int CT = CPW / 16;
    static_assert(CPW % 16 == 0 && F % 16 == 0, "");
    const int tid = threadIdx.x, wave = tid >> 6, lane = tid & 63;
    const int q = lane >> 4, m16 = lane & 15;
    const int row0 = blockIdx.x * 64;

    __shared__ __align__(16) bf16_t s_x[64 * LDA];
    stage_tile<F, LDA, NT, XF32>(s_x, xsrc_v, row0, tid);
    __syncthreads();

    #pragma unroll
    for (int ct = 0; ct < CT; ++ct) {
        const int lc0 = wave * CPW + ct * 16;   // linear col block (within one gate)
        const int g = lc0 / F, c0 = lc0 - g * F;
        const float bias = b0[lc0 + m16] + b1v[lc0 + m16];
        f32x4 acc[4];
        #pragma unroll
        for (int rt = 0; rt < 4; ++rt)
            #pragma unroll
            for (int r = 0; r < 4; ++r) acc[rt][r] = bias;
        #pragma unroll
        for (int kk = 0; kk < KK; ++kk) {
            const int ko = kk * 32 + q * 8;
            bf16x8 b = *reinterpret_cast<const bf16x8*>(W + (size_t)(lc0 + m16) * F + ko);
            #pragma unroll
            for (int rt = 0; rt < 4; ++rt) {
                bf16x8 a = *reinterpret_cast<const bf16x8*>(&s_x[(rt * 16 + m16) * LDA + ko]);
                acc[rt] = __builtin_amdgcn_mfma_f32_16x16x32_bf16(a, b, acc[rt], 0, 0, 0);
            }
        }
        #pragma unroll
        for (int rt = 0; rt < 4; ++rt)
            #pragma unroll
            for (int r = 0; r < 4; ++r) {
                int row = row0 + rt * 16 + q * 4 + r;
                if (row < NN)
                    xg[(size_t)row * G + (size_t)(c0 + m16) * 4 + g] = (bf16_t)acc[rt][r];
            }
    }
}

// LSTM recurrence over gathered neighbors + fused fc epilogue.
// Block b processes nodes perm[b*64 .. b*64+63] (degree-sorted DESC) and
// loops only to tmax = max(deg in block). 16 waves = NWR(2) row-waves x
// NWC(8) col-waves on the 64-node tile.
// gates = gather(xg) + h @ Whh^T ; out = x_self@Wself^T + h_fin@Wneigh^T + b
template<int F, int NWC, int NWR, int OUTF, bool RELU, bool XF32, typename OutT>
__global__ __launch_bounds__(NWC * NWR * 64, 4)
void sage_rec(const void* __restrict__ xself_v,
              const bf16_t* __restrict__ xg,
              const int* __restrict__ nbr_idx, const int* __restrict__ deg,
              const int* __restrict__ perm,
              const bf16_t* __restrict__ Whh,
              const bf16_t* __restrict__ Wself, const bf16_t* __restrict__ Wneigh,
              const float* __restrict__ bout, OutT* __restrict__ outp)
{
    constexpr int M = 64, LDA = F + 8, KK = F / 32;
    constexpr int NW = NWC * NWR, NT = NW * 64;
    constexpr int RT = M / (16 * NWR);          // row-tiles per wave
    constexpr int CPW = F / NWC, CT = CPW / 16; // col-tiles per wave
    constexpr int G4 = 4 * F;
    static_assert(CPW % 16 == 0 && M % (16 * NWR) == 0, "");
    const int tid = threadIdx.x, wave = tid >> 6, lane = tid & 63;
    const int q = lane >> 4, m16 = lane & 15;
    const int wc = wave % NWC, wr = wave / NWC;
    const int ROWB = wr * (RT * 16);            // this wave's row base in tile
    const int slot0 = blockIdx.x * M;

    __shared__ __align__(16) bf16_t s_h[2][M * LDA];   // double-buffered h
    __shared__ int s_idx[M * DMAXX];
    __shared__ int s_deg[M];
    __shared__ int s_node[M];
    __shared__ int s_tmax;

    for (int i = tid; i < M; i += NT) {
        int slot = slot0 + i; if (slot >= NN) slot = NN - 1;
        int node = perm[slot];
        s_node[i] = node;
        s_deg[i] = deg[node];
    }
    __syncthreads();
    for (int i = tid; i < M * DMAXX; i += NT) {
        int node = s_node[i >> 4];
        int v = nbr_idx[node * DMAXX + (i & 15)];
        if (v < 0) v = 0; if (v >= NN) v = NN - 1;
        s_idx[i] = v;
    }
    for (int i = tid; i < M * LDA; i += NT) s_h[0][i] = (bf16_t)0.0f;
    if (tid == 0) {
        int mx = 1;
        for (int i = 0; i < M; ++i) { int d = s_deg[i]; mx = d > mx ? d : mx; }
        s_tmax = mx;
    }
    __syncthreads();
    const int tmax = s_tmax;   // uniform-degree blocks: ~= block's degree bucket

    int dg[RT][4];
    #pragma unroll
    for (int rt = 0; rt < RT; ++rt)
        #pragma unroll
        for (int r = 0; r < 4; ++r)
            dg[rt][r] = s_deg[ROWB + rt * 16 + q * 4 + r];

    f32x4 c_[RT][CT];
    #pragma unroll
    for (int rt = 0; rt < RT; ++rt)
        #pragma unroll
        for (int ct = 0; ct < CT; ++ct)
            #pragma unroll
            for (int r = 0; r < 4; ++r) c_[rt][ct][r] = 0.0f;

    // gather gate-init for step 0 (xg = x@Wih^T + biases), 8B/elem
    u16x4 u[CT][RT][4];
    #pragma unroll
    for (int ct = 0; ct < CT; ++ct)
        #pragma unroll
        for (int rt = 0; rt < RT; ++rt)
            #pragma unroll
            for (int r = 0; r < 4; ++r) {
                int row = s_idx[(ROWB + rt * 16 + q * 4 + r) * DMAXX];
                u[ct][rt][r] = *reinterpret_cast<const u16x4*>(
                    xg + (size_t)row * G4 + (size_t)(wc * CPW + ct * 16 + m16) * 4);
            }

    #pragma unroll 1
    for (int t = 0; t < tmax; ++t) {
        const bf16_t* cur = s_h[t & 1];
        bf16_t* nxt = s_h[(t + 1) & 1];
        #pragma unroll
        for (int ct = 0; ct < CT; ++ct) {
            f32x4 acc[RT][4];
            #pragma unroll
            for (int rt = 0; rt < RT; ++rt)
                #pragma unroll
                for (int g = 0; g < 4; ++g)
                    #pragma unroll
                    for (int r = 0; r < 4; ++r) acc[rt][g][r] = 0.0f;
            #pragma unroll
            for (int kk = 0; kk < KK; ++kk) {
                const int ko = kk * 32 + q * 8;
                bf16x8 ah[RT];
                #pragma unroll
                for (int rt = 0; rt < RT; ++rt)
                    ah[rt] = *reinterpret_cast<const bf16x8*>(&cur[(ROWB + rt * 16 + m16) * LDA + ko]);
                #pragma unroll
                for (int g = 0; g < 4; ++g) {
                    bf16x8 bh = *reinterpret_cast<const bf16x8*>(
                        Whh + (size_t)(g * F + wc * CPW + ct * 16 + m16) * F + ko);
                    #pragma unroll
                    for (int rt = 0; rt < RT; ++rt)
                        acc[rt][g] = __builtin_amdgcn_mfma_f32_16x16x32_bf16(ah[rt], bh, acc[rt][g], 0, 0, 0);
                }
            }
            // pointwise LSTM update + masked store:
            //   t <  deg : write h_new (and update c)
            //   t == deg : copy frozen h from cur (this thread's t-1 write)
            //   t >  deg : skip -- nxt already holds the frozen value
            #pragma unroll
            for (int rt = 0; rt < RT; ++rt)
                #pragma unroll
                for (int r = 0; r < 4; ++r) {
                    float iv = fsig (acc[rt][0][r] + bf2f(u[ct][rt][r].x));
                    float fv = fsig (acc[rt][1][r] + bf2f(u[ct][rt][r].y));
                    float gv = ftanh(acc[rt][2][r] + bf2f(u[ct][rt][r].z));
                    float ov = fsig (acc[rt][3][r] + bf2f(u[ct][rt][r].w));
                    float cn = fv * c_[rt][ct][r] + iv * gv;
                    float hv = ov * ftanh(cn);
                    const int pos = (ROWB + rt * 16 + q * 4 + r) * LDA + wc * CPW + ct * 16 + m16;
                    int d = dg[rt][r];
                    if (t < d) {
                        c_[rt][ct][r] = cn;
                        nxt[pos] = (bf16_t)hv;
                    } else if (t == d) {
                        reinterpret_cast<unsigned short*>(nxt)[pos] =
                            reinterpret_cast<const unsigned short*>(cur)[pos];
                    }
                }
            // refill u[ct] for step t+1: issued here, in flight across the
            // barrier, consumed after next step's MFMA -> latency hidden
            if (t + 1 < tmax) {
                #pragma unroll
                for (int rt = 0; rt < RT; ++rt)
                    #pragma unroll
                    for (int r = 0; r < 4; ++r) {
                        int row = s_idx[(ROWB + rt * 16 + q * 4 + r) * DMAXX + t + 1];
                        u[ct][rt][r] = *reinterpret_cast<const u16x4*>(
                            xg + (size_t)row * G4 + (size_t)(wc * CPW + ct * 16 + m16) * 4);
                    }
            }
        }
        __syncthreads();   // nxt fully written; cur fully consumed
    }

    // final h is in s_h[tmax&1]; stage self-rows into the other buffer
    const int fb = tmax & 1;
    const bf16_t* hfin = s_h[fb];
    bf16_t* hstage = s_h[fb ^ 1];
    stage_rows<F, LDA, NT, XF32>(hstage, xself_v, s_node, tid);
    __syncthreads();

    // epilogue: out = x_self @ Wself^T + h_fin @ Wneigh^T + bout (+relu)
    constexpr int NCT = OUTF / 16;
    constexpr int TILES = NCT * 4;     // 4 row-tiles of the 64-node tile
    constexpr int TPW = TILES / NW;
    static_assert(TILES % NW == 0, "");
    #pragma unroll
    for (int tt = 0; tt < TPW; ++tt) {
        int tile = wave * TPW + tt;
        int ot = tile % NCT, rt = tile / NCT;
        f32x4 o;
        o[0] = 0.f; o[1] = 0.f; o[2] = 0.f; o[3] = 0.f;
        #pragma unroll
        for (int kk = 0; kk < KK; ++kk) {
            const int ko = kk * 32 + q * 8;
            bf16x8 axs = *reinterpret_cast<const bf16x8*>(&hstage[(rt * 16 + m16) * LDA + ko]);
            bf16x8 am  = *reinterpret_cast<const bf16x8*>(&hfin[(rt * 16 + m16) * LDA + ko]);
            bf16x8 bs = *reinterpret_cast<const bf16x8*>(Wself  + (size_t)(ot * 16 + m16) * F + ko);
            bf16x8 bn = *reinterpret_cast<const bf16x8*>(Wneigh + (size_t)(ot * 16 + m16) * F + ko);
            o = __builtin_amdgcn_mfma_f32_16x16x32_bf16(axs, bs, o, 0, 0, 0);
            o = __builtin_amdgcn_mfma_f32_16x16x32_bf16(am,  bn, o, 0, 0, 0);
        }
        int ocol = ot * 16 + m16;
        float bias = bout[ocol];
        #pragma unroll
        for (int r = 0; r < 4; ++r) {
            int node = s_node[rt * 16 + q * 4 + r];
            float v = o[r] + bias;
            if (RELU) v = fmaxf(v, 0.0f);
            outp[(size_t)node * OUTF + ocol] = (OutT)v;
        }
    }
}

extern "C" void kernel_launch(void* const* d_in, const int* in_sizes, int n_in,
                              void* d_out, int out_size, void* d_ws, size_t ws_size,
                              hipStream_t stream)
{
    const float* feat    = (const float*)d_in[0];
    const int*   nbr     = (const int*)d_in[1];
    const int*   degp    = (const int*)d_in[2];
    const float* Wih1    = (const float*)d_in[3];
    const float* Whh1    = (const float*)d_in[4];
    const float* bih1    = (const float*)d_in[5];
    const float* bhh1    = (const float*)d_in[6];
    const float* Wself1  = (const float*)d_in[7];
    const float* Wneigh1 = (const float*)d_in[8];
    const float* b1      = (const float*)d_in[9];
    const float* Wih2    = (const float*)d_in[10];
    const float* Whh2    = (const float*)d_in[11];
    const float* bih2    = (const float*)d_in[12];
    const float* bhh2    = (const float*)d_in[13];
    const float* Wself2  = (const float*)d_in[14];
    const float* Wneigh2 = (const float*)d_in[15];
    const float* b2      = (const float*)d_in[16];

    bf16_t *hglob, *wglob, *xg1, *xg2;
    int *permg;
    hipGetSymbolAddress((void**)&hglob, HIP_SYMBOL(g_hbuf));
    hipGetSymbolAddress((void**)&wglob, HIP_SYMBOL(g_wbuf));
    hipGetSymbolAddress((void**)&xg1,   HIP_SYMBOL(g_xg1));
    hipGetSymbolAddress((void**)&xg2,   HIP_SYMBOL(g_xg2));
    hipGetSymbolAddress((void**)&permg, HIP_SYMBOL(g_perm));

    cvt_weights<<<W_TOTAL / 4 / 256, 256, 0, stream>>>(
        Wih1, Whh1, Wself1, Wneigh1, Wih2, Whh2, Wself2, Wneigh2);

    build_perm<<<1, 256, 0, stream>>>(degp, permg);

    const int grid = (NN + 63) / 64;   // 469 WGs

    xg_gemm<128, 512, 8, true><<<grid, 512, 0, stream>>>(
        feat, wglob + OFF_WIH1, bih1, bhh1, xg1);

    sage_rec<128, 8, 2, 256, true, true, bf16_t><<<grid, 1024, 0, stream>>>(
        feat, xg1, nbr, degp, permg, wglob + OFF_WHH1,
        wglob + OFF_WSELF1, wglob + OFF_WNEIGH1, b1, hglob);

    xg_gemm<256, 1024, 8, false><<<grid, 512, 0, stream>>>(
        hglob, wglob + OFF_WIH2, bih2, bhh2, xg2);

    sage_rec<256, 8, 2, 64, false, false, float><<<grid, 1024, 0, stream>>>(
        hglob, xg2, nbr, degp, permg, wglob + OFF_WHH2,
        wglob + OFF_WSELF2, wglob + OFF_WNEIGH2, b2, (float*)d_out);
}

// Round 6
// 1422.505 us; speedup vs baseline: 1.2023x; 1.2023x over previous
//
#include <hip/hip_runtime.h>
#include <hip/hip_bf16.h>
#include <stdint.h>

// SAGE (GraphSAGE, LSTM aggregator). f32 I/O, bf16 MFMA internally.
// N=30000, DMAX=16, dims 128 -> 256 -> 64.
// R12 RESUBMIT (R12 bench = infra failure "container failed twice"; no
// counter evidence against the change -> resubmit unchanged).
// R11 -> R12 (R11: 1710us. Scheduling theory CONFIRMED: occupancy 16.6->43.8%,
// hbm 1.6->2.8 TB/s. But 16-wave blocks cap arch+acc at 128 regs/wave; the
// cross-barrier u[CT][RT][4] prefetch + acc + c_ overflowed the 64-arch half
// (VGPR_Count 64) -> scratch spills: FETCH +1.6GB, WRITE +0.48GB ate the win.
// Also learned: R9's "128 VGPR" = 128 arch + 64 acc = 192/wave -> R7/R9 only
// ever ran 1 blk/CU (8 waves, 25% occ cap)):
//   1. KEEP 16-wave M=64 blocks + descending LPT sort (the packing win).
//   2. DROP the cross-barrier u prefetch -> R9-style in-step gather: transient
//      u[RT][4] (16 regs) issued at top of each ct iter, latency hidden behind
//      that iter's 64 MFMAs. Per-wave live state now fits 64 arch + 64 acc.
// Verified layouts (learn_hip m89/m91): A[m=lane&15][k=q*8+j],
// D[row=q*4+r][col=lane&15]; W[4F,F] row-major == gemm-BT B-frag layout.

#define NN 30000
#define DMAXX 16

typedef __bf16 bf16_t;
typedef __bf16 bf16x8 __attribute__((ext_vector_type(8)));
typedef float f32x4 __attribute__((ext_vector_type(4)));
typedef unsigned short u16x4 __attribute__((ext_vector_type(4)));

// persistent scratch (fully rewritten every call; no cross-call state reuse)
__device__ __align__(16) bf16_t g_hbuf[(size_t)NN * 256];    // layer-1 output h1
__device__ __align__(16) bf16_t g_xg1[(size_t)NN * 512];     // feat@Wih1^T + biases
__device__ __align__(16) bf16_t g_xg2[(size_t)NN * 1024];    // h1@Wih2^T + biases
__device__ __align__(16) bf16_t g_wbuf[753664];              // bf16 weight copies
__device__ int g_perm[NN];                                   // degree-sorted node ids

#define OFF_WIH1 0
#define OFF_WHH1 65536
#define OFF_WSELF1 131072
#define OFF_WNEIGH1 163840
#define OFF_WIH2 196608
#define OFF_WHH2 458752
#define OFF_WSELF2 720896
#define OFF_WNEIGH2 737280
#define W_TOTAL 753664

__global__ __launch_bounds__(256)
void cvt_weights(const float* __restrict__ s0, const float* __restrict__ s1,
                 const float* __restrict__ s2, const float* __restrict__ s3,
                 const float* __restrict__ s4, const float* __restrict__ s5,
                 const float* __restrict__ s6, const float* __restrict__ s7)
{
    int i = (blockIdx.x * 256 + threadIdx.x) * 4;
    if (i >= W_TOTAL) return;
    const float* src; int off;
    if      (i < OFF_WHH1)   { src = s0; off = OFF_WIH1; }
    else if (i < OFF_WSELF1) { src = s1; off = OFF_WHH1; }
    else if (i < OFF_WNEIGH1){ src = s2; off = OFF_WSELF1; }
    else if (i < OFF_WIH2)   { src = s3; off = OFF_WNEIGH1; }
    else if (i < OFF_WHH2)   { src = s4; off = OFF_WIH2; }
    else if (i < OFF_WSELF2) { src = s5; off = OFF_WHH2; }
    else if (i < OFF_WNEIGH2){ src = s6; off = OFF_WSELF2; }
    else                     { src = s7; off = OFF_WNEIGH2; }
    float4 v = *reinterpret_cast<const float4*>(src + (i - off));
    bf16_t o[4] __attribute__((aligned(8)));
    o[0] = (bf16_t)v.x; o[1] = (bf16_t)v.y; o[2] = (bf16_t)v.z; o[3] = (bf16_t)v.w;
    *reinterpret_cast<uint2*>(&g_wbuf[i]) = *reinterpret_cast<const uint2*>(o);
}

// counting sort of node ids by DESCENDING degree (LPT block scheduling).
// Non-stable (atomic slot grab) -- per-node results are independent of
// grouping, so any permutation is correct.
__global__ __launch_bounds__(256)
void build_perm(const int* __restrict__ deg, int* __restrict__ perm)
{
    __shared__ int s_base[DMAXX + 1];
    const int tid = threadIdx.x;
    if (tid <= DMAXX) s_base[tid] = 0;
    __syncthreads();
    for (int i = tid; i < NN; i += 256) {
        int d = deg[i]; d = d < 0 ? 0 : (d > DMAXX ? DMAXX : d);
        atomicAdd(&s_base[d], 1);
    }
    __syncthreads();
    if (tid == 0) {
        int acc = 0;
        for (int d = DMAXX; d >= 0; --d) { int c = s_base[d]; s_base[d] = acc; acc += c; }
    }
    __syncthreads();
    for (int i = tid; i < NN; i += 256) {
        int d = deg[i]; d = d < 0 ? 0 : (d > DMAXX ? DMAXX : d);
        int p = atomicAdd(&s_base[d], 1);
        perm[p] = i;
    }
}

__device__ __forceinline__ float fsig(float x) { return 1.0f / (1.0f + __expf(-x)); }
__device__ __forceinline__ float ftanh(float x) { return 1.0f - 2.0f / (__expf(2.0f * x) + 1.0f); }
__device__ __forceinline__ float bf2f(unsigned short s) {
    union { unsigned u; float f; } v; v.u = ((unsigned)s) << 16; return v.f;
}

// stage a 64-row x-tile (linear rows, row-clamped) into LDS as bf16
template<int F, int LDA, int NT, bool XF32>
__device__ __forceinline__ void stage_tile(bf16_t* dst, const void* src, int row0, int tid)
{
    constexpr int UN = F / 8;          // 16B(bf16) units per row
    for (int e = tid; e < 64 * UN; e += NT) {
        int m = e / UN, sub = e - m * UN;
        int row = row0 + m; if (row >= NN) row = NN - 1;
        if constexpr (XF32) {
            const float* p = (const float*)src + (size_t)row * F + sub * 8;
            float4 f0 = reinterpret_cast<const float4*>(p)[0];
            float4 f1 = reinterpret_cast<const float4*>(p)[1];
            bf16_t t[8] __attribute__((aligned(16)));
            t[0]=(bf16_t)f0.x; t[1]=(bf16_t)f0.y; t[2]=(bf16_t)f0.z; t[3]=(bf16_t)f0.w;
            t[4]=(bf16_t)f1.x; t[5]=(bf16_t)f1.y; t[6]=(bf16_t)f1.z; t[7]=(bf16_t)f1.w;
            *reinterpret_cast<uint4*>(&dst[m * LDA + sub * 8]) = *reinterpret_cast<const uint4*>(t);
        } else {
            const bf16_t* p = (const bf16_t*)src + (size_t)row * F + sub * 8;
            *reinterpret_cast<uint4*>(&dst[m * LDA + sub * 8]) = *reinterpret_cast<const uint4*>(p);
        }
    }
}

// stage a 64-row x-tile with per-row node ids (from LDS array) into LDS
template<int F, int LDA, int NT, bool XF32>
__device__ __forceinline__ void stage_rows(bf16_t* dst, const void* src, const int* nodes, int tid)
{
    constexpr int UN = F / 8;
    for (int e = tid; e < 64 * UN; e += NT) {
        int m = e / UN, sub = e - m * UN;
        int row = nodes[m];
        if constexpr (XF32) {
            const float* p = (const float*)src + (size_t)row * F + sub * 8;
            float4 f0 = reinterpret_cast<const float4*>(p)[0];
            float4 f1 = reinterpret_cast<const float4*>(p)[1];
            bf16_t t[8] __attribute__((aligned(16)));
            t[0]=(bf16_t)f0.x; t[1]=(bf16_t)f0.y; t[2]=(bf16_t)f0.z; t[3]=(bf16_t)f0.w;
            t[4]=(bf16_t)f1.x; t[5]=(bf16_t)f1.y; t[6]=(bf16_t)f1.z; t[7]=(bf16_t)f1.w;
            *reinterpret_cast<uint4*>(&dst[m * LDA + sub * 8]) = *reinterpret_cast<const uint4*>(t);
        } else {
            const bf16_t* p = (const bf16_t*)src + (size_t)row * F + sub * 8;
            *reinterpret_cast<uint4*>(&dst[m * LDA + sub * 8]) = *reinterpret_cast<const uint4*>(p);
        }
    }
}

// xg[N, 4F] (gate-interleaved [c][g]) = x[N,F] @ W[4F,F]^T + b0 + b1
template<int F, int G, int NW, bool XF32>
__global__ __launch_bounds__(NW * 64, 2)
void xg_gemm(const void* __restrict__ xsrc_v, const bf16_t* __restrict__ W,
             const float* __restrict__ b0, const float* __restrict__ b1v,
             bf16_t* __restrict__ xg)
{
    constexpr int LDA = F + 8, KK = F / 32, NT = NW * 64;
    constexpr int CPW = G / NW;        // linear out-cols per wave
    constexpr int CT = CPW / 16;
    static_assert(CPW % 16 == 0 && F % 16 == 0, "");
    const int tid = threadIdx.x, wave = tid >> 6, lane = tid & 63;
    const int q = lane >> 4, m16 = lane & 15;
    const int row0 = blockIdx.x * 64;

    __shared__ __align__(16) bf16_t s_x[64 * LDA];
    stage_tile<F, LDA, NT, XF32>(s_x, xsrc_v, row0, tid);
    __syncthreads();

    #pragma unroll
    for (int ct = 0; ct < CT; ++ct) {
        const int lc0 = wave * CPW + ct * 16;   // linear col block (within one gate)
        const int g = lc0 / F, c0 = lc0 - g * F;
        const float bias = b0[lc0 + m16] + b1v[lc0 + m16];
        f32x4 acc[4];
        #pragma unroll
        for (int rt = 0; rt < 4; ++rt)
            #pragma unroll
            for (int r = 0; r < 4; ++r) acc[rt][r] = bias;
        #pragma unroll
        for (int kk = 0; kk < KK; ++kk) {
            const int ko = kk * 32 + q * 8;
            bf16x8 b = *reinterpret_cast<const bf16x8*>(W + (size_t)(lc0 + m16) * F + ko);
            #pragma unroll
            for (int rt = 0; rt < 4; ++rt) {
                bf16x8 a = *reinterpret_cast<const bf16x8*>(&s_x[(rt * 16 + m16) * LDA + ko]);
                acc[rt] = __builtin_amdgcn_mfma_f32_16x16x32_bf16(a, b, acc[rt], 0, 0, 0);
            }
        }
        #pragma unroll
        for (int rt = 0; rt < 4; ++rt)
            #pragma unroll
            for (int r = 0; r < 4; ++r) {
                int row = row0 + rt * 16 + q * 4 + r;
                if (row < NN)
                    xg[(size_t)row * G + (size_t)(c0 + m16) * 4 + g] = (bf16_t)acc[rt][r];
            }
    }
}

// LSTM recurrence over gathered neighbors + fused fc epilogue.
// Block b processes nodes perm[b*64 .. b*64+63] (degree-sorted DESC) and
// loops only to tmax = max(deg in block). 16 waves = NWR(2) row-waves x
// NWC(8) col-waves on the 64-node tile.
// gates = gather(xg) + h @ Whh^T ; out = x_self@Wself^T + h_fin@Wneigh^T + b
template<int F, int NWC, int NWR, int OUTF, bool RELU, bool XF32, typename OutT>
__global__ __launch_bounds__(NWC * NWR * 64, 4)
void sage_rec(const void* __restrict__ xself_v,
              const bf16_t* __restrict__ xg,
              const int* __restrict__ nbr_idx, const int* __restrict__ deg,
              const int* __restrict__ perm,
              const bf16_t* __restrict__ Whh,
              const bf16_t* __restrict__ Wself, const bf16_t* __restrict__ Wneigh,
              const float* __restrict__ bout, OutT* __restrict__ outp)
{
    constexpr int M = 64, LDA = F + 8, KK = F / 32;
    constexpr int NW = NWC * NWR, NT = NW * 64;
    constexpr int RT = M / (16 * NWR);          // row-tiles per wave
    constexpr int CPW = F / NWC, CT = CPW / 16; // col-tiles per wave
    constexpr int G4 = 4 * F;
    static_assert(CPW % 16 == 0 && M % (16 * NWR) == 0, "");
    const int tid = threadIdx.x, wave = tid >> 6, lane = tid & 63;
    const int q = lane >> 4, m16 = lane & 15;
    const int wc = wave % NWC, wr = wave / NWC;
    const int ROWB = wr * (RT * 16);            // this wave's row base in tile
    const int slot0 = blockIdx.x * M;

    __shared__ __align__(16) bf16_t s_h[2][M * LDA];   // double-buffered h
    __shared__ int s_idx[M * DMAXX];
    __shared__ int s_deg[M];
    __shared__ int s_node[M];
    __shared__ int s_tmax;

    for (int i = tid; i < M; i += NT) {
        int slot = slot0 + i; if (slot >= NN) slot = NN - 1;
        int node = perm[slot];
        s_node[i] = node;
        s_deg[i] = deg[node];
    }
    __syncthreads();
    for (int i = tid; i < M * DMAXX; i += NT) {
        int node = s_node[i >> 4];
        int v = nbr_idx[node * DMAXX + (i & 15)];
        if (v < 0) v = 0; if (v >= NN) v = NN - 1;
        s_idx[i] = v;
    }
    for (int i = tid; i < M * LDA; i += NT) s_h[0][i] = (bf16_t)0.0f;
    if (tid == 0) {
        int mx = 1;
        for (int i = 0; i < M; ++i) { int d = s_deg[i]; mx = d > mx ? d : mx; }
        s_tmax = mx;
    }
    __syncthreads();
    const int tmax = s_tmax;   // uniform-degree blocks: ~= block's degree bucket

    int dg[RT][4];
    #pragma unroll
    for (int rt = 0; rt < RT; ++rt)
        #pragma unroll
        for (int r = 0; r < 4; ++r)
            dg[rt][r] = s_deg[ROWB + rt * 16 + q * 4 + r];

    f32x4 c_[RT][CT];
    #pragma unroll
    for (int rt = 0; rt < RT; ++rt)
        #pragma unroll
        for (int ct = 0; ct < CT; ++ct)
            #pragma unroll
            for (int r = 0; r < 4; ++r) c_[rt][ct][r] = 0.0f;

    #pragma unroll 1
    for (int t = 0; t < tmax; ++t) {
        const bf16_t* cur = s_h[t & 1];
        bf16_t* nxt = s_h[(t + 1) & 1];
        #pragma unroll
        for (int ct = 0; ct < CT; ++ct) {
            // in-step gather gate-init (xg = x@Wih^T + biases), 8B/elem;
            // transient regs, latency hidden behind this iter's MFMAs
            u16x4 u[RT][4];
            #pragma unroll
            for (int rt = 0; rt < RT; ++rt)
                #pragma unroll
                for (int r = 0; r < 4; ++r) {
                    int row = s_idx[(ROWB + rt * 16 + q * 4 + r) * DMAXX + t];
                    u[rt][r] = *reinterpret_cast<const u16x4*>(
                        xg + (size_t)row * G4 + (size_t)(wc * CPW + ct * 16 + m16) * 4);
                }
            f32x4 acc[RT][4];
            #pragma unroll
            for (int rt = 0; rt < RT; ++rt)
                #pragma unroll
                for (int g = 0; g < 4; ++g)
                    #pragma unroll
                    for (int r = 0; r < 4; ++r) acc[rt][g][r] = 0.0f;
            #pragma unroll
            for (int kk = 0; kk < KK; ++kk) {
                const int ko = kk * 32 + q * 8;
                bf16x8 ah[RT];
                #pragma unroll
                for (int rt = 0; rt < RT; ++rt)
                    ah[rt] = *reinterpret_cast<const bf16x8*>(&cur[(ROWB + rt * 16 + m16) * LDA + ko]);
                #pragma unroll
                for (int g = 0; g < 4; ++g) {
                    bf16x8 bh = *reinterpret_cast<const bf16x8*>(
                        Whh + (size_t)(g * F + wc * CPW + ct * 16 + m16) * F + ko);
                    #pragma unroll
                    for (int rt = 0; rt < RT; ++rt)
                        acc[rt][g] = __builtin_amdgcn_mfma_f32_16x16x32_bf16(ah[rt], bh, acc[rt][g], 0, 0, 0);
                }
            }
            // pointwise LSTM update + masked store:
            //   t <  deg : write h_new (and update c)
            //   t == deg : copy frozen h from cur (this thread's t-1 write)
            //   t >  deg : skip -- nxt already holds the frozen value
            #pragma unroll
            for (int rt = 0; rt < RT; ++rt)
                #pragma unroll
                for (int r = 0; r < 4; ++r) {
                    float iv = fsig (acc[rt][0][r] + bf2f(u[rt][r].x));
                    float fv = fsig (acc[rt][1][r] + bf2f(u[rt][r].y));
                    float gv = ftanh(acc[rt][2][r] + bf2f(u[rt][r].z));
                    float ov = fsig (acc[rt][3][r] + bf2f(u[rt][r].w));
                    float cn = fv * c_[rt][ct][r] + iv * gv;
                    float hv = ov * ftanh(cn);
                    const int pos = (ROWB + rt * 16 + q * 4 + r) * LDA + wc * CPW + ct * 16 + m16;
                    int d = dg[rt][r];
                    if (t < d) {
                        c_[rt][ct][r] = cn;
                        nxt[pos] = (bf16_t)hv;
                    } else if (t == d) {
                        reinterpret_cast<unsigned short*>(nxt)[pos] =
                            reinterpret_cast<const unsigned short*>(cur)[pos];
                    }
                }
        }
        __syncthreads();   // nxt fully written; cur fully consumed
    }

    // final h is in s_h[tmax&1]; stage self-rows into the other buffer
    const int fb = tmax & 1;
    const bf16_t* hfin = s_h[fb];
    bf16_t* hstage = s_h[fb ^ 1];
    stage_rows<F, LDA, NT, XF32>(hstage, xself_v, s_node, tid);
    __syncthreads();

    // epilogue: out = x_self @ Wself^T + h_fin @ Wneigh^T + bout (+relu)
    constexpr int NCT = OUTF / 16;
    constexpr int TILES = NCT * 4;     // 4 row-tiles of the 64-node tile
    constexpr int TPW = TILES / NW;
    static_assert(TILES % NW == 0, "");
    #pragma unroll
    for (int tt = 0; tt < TPW; ++tt) {
        int tile = wave * TPW + tt;
        int ot = tile % NCT, rt = tile / NCT;
        f32x4 o;
        o[0] = 0.f; o[1] = 0.f; o[2] = 0.f; o[3] = 0.f;
        #pragma unroll
        for (int kk = 0; kk < KK; ++kk) {
            const int ko = kk * 32 + q * 8;
            bf16x8 axs = *reinterpret_cast<const bf16x8*>(&hstage[(rt * 16 + m16) * LDA + ko]);
            bf16x8 am  = *reinterpret_cast<const bf16x8*>(&hfin[(rt * 16 + m16) * LDA + ko]);
            bf16x8 bs = *reinterpret_cast<const bf16x8*>(Wself  + (size_t)(ot * 16 + m16) * F + ko);
            bf16x8 bn = *reinterpret_cast<const bf16x8*>(Wneigh + (size_t)(ot * 16 + m16) * F + ko);
            o = __builtin_amdgcn_mfma_f32_16x16x32_bf16(axs, bs, o, 0, 0, 0);
            o = __builtin_amdgcn_mfma_f32_16x16x32_bf16(am,  bn, o, 0, 0, 0);
        }
        int ocol = ot * 16 + m16;
        float bias = bout[ocol];
        #pragma unroll
        for (int r = 0; r < 4; ++r) {
            int node = s_node[rt * 16 + q * 4 + r];
            float v = o[r] + bias;
            if (RELU) v = fmaxf(v, 0.0f);
            outp[(size_t)node * OUTF + ocol] = (OutT)v;
        }
    }
}

extern "C" void kernel_launch(void* const* d_in, const int* in_sizes, int n_in,
                              void* d_out, int out_size, void* d_ws, size_t ws_size,
                              hipStream_t stream)
{
    const float* feat    = (const float*)d_in[0];
    const int*   nbr     = (const int*)d_in[1];
    const int*   degp    = (const int*)d_in[2];
    const float* Wih1    = (const float*)d_in[3];
    const float* Whh1    = (const float*)d_in[4];
    const float* bih1    = (const float*)d_in[5];
    const float* bhh1    = (const float*)d_in[6];
    const float* Wself1  = (const float*)d_in[7];
    const float* Wneigh1 = (const float*)d_in[8];
    const float* b1      = (const float*)d_in[9];
    const float* Wih2    = (const float*)d_in[10];
    const float* Whh2    = (const float*)d_in[11];
    const float* bih2    = (const float*)d_in[12];
    const float* bhh2    = (const float*)d_in[13];
    const float* Wself2  = (const float*)d_in[14];
    const float* Wneigh2 = (const float*)d_in[15];
    const float* b2      = (const float*)d_in[16];

    bf16_t *hglob, *wglob, *xg1, *xg2;
    int *permg;
    hipGetSymbolAddress((void**)&hglob, HIP_SYMBOL(g_hbuf));
    hipGetSymbolAddress((void**)&wglob, HIP_SYMBOL(g_wbuf));
    hipGetSymbolAddress((void**)&xg1,   HIP_SYMBOL(g_xg1));
    hipGetSymbolAddress((void**)&xg2,   HIP_SYMBOL(g_xg2));
    hipGetSymbolAddress((void**)&permg, HIP_SYMBOL(g_perm));

    cvt_weights<<<W_TOTAL / 4 / 256, 256, 0, stream>>>(
        Wih1, Whh1, Wself1, Wneigh1, Wih2, Whh2, Wself2, Wneigh2);

    build_perm<<<1, 256, 0, stream>>>(degp, permg);

    const int grid = (NN + 63) / 64;   // 469 WGs

    xg_gemm<128, 512, 8, true><<<grid, 512, 0, stream>>>(
        feat, wglob + OFF_WIH1, bih1, bhh1, xg1);

    sage_rec<128, 8, 2, 256, true, true, bf16_t><<<grid, 1024, 0, stream>>>(
        feat, xg1, nbr, degp, permg, wglob + OFF_WHH1,
        wglob + OFF_WSELF1, wglob + OFF_WNEIGH1, b1, hglob);

    xg_gemm<256, 1024, 8, false><<<grid, 512, 0, stream>>>(
        hglob, wglob + OFF_WIH2, bih2, bhh2, xg2);

    sage_rec<256, 8, 2, 64, false, false, float><<<grid, 1024, 0, stream>>>(
        hglob, xg2, nbr, degp, permg, wglob + OFF_WHH2,
        wglob + OFF_WSELF2, wglob + OFF_WNEIGH2, b2, (float*)d_out);
}

// Round 7
// 1025.539 us; speedup vs baseline: 1.6676x; 1.3871x over previous
//
#include <hip/hip_runtime.h>
#include <hip/hip_bf16.h>
#include <stdint.h>

// SAGE (GraphSAGE, LSTM aggregator). f32 I/O, bf16 MFMA internally.
// N=30000, DMAX=16, dims 128 -> 256 -> 64.
// R12 -> R13 (R12: 1422us, rec2 994us. Spills PERSIST: WRITE 470MB vs ~230MB
// baseline = ~240MB spill stores; FETCH 2.44GB has ~460MB spill-fill. CT=2
// interleaved state (u16+ah8+acc32AGPR+c16+addrs) still > 128-reg budget of
// 16-wave blocks. ALSO: NWR=2 row-groups duplicate Whh columns -> 1MB issued
// per block-step (4GB total), ~1.4GB L2-miss refetch):
//   1. Sequential PASSES of 2 row-tiles: each pass gathers u (16 regs),
//      MFMAs 2 row-tiles x 4 gates (acc 32 AGPR transient), pointwise, dies.
//      Named c0..c3 cell vars (no runtime-indexed arrays -> no scratch),
//      sched_barrier(0) between passes stops re-merging. Live state ~50 arch
//      + 48 acc << 128 -> NO SPILL.
//   2. F=256: NWC=16/NWR=1 (wave owns 16 cols, all 64 rows in 2 passes) ->
//      Whh issued ONCE per block-step (512KB); pass-2 re-read of the wave's
//      32KB slice hits L1/L2. F=128: NWC=8/NWR=2, 1 pass (Whh1 tiny).
//   3. dg regs dropped (s_deg read from LDS in pointwise).
// Arithmetic order per (row,g,kk) unchanged -> bit-identical output.
// Verified layouts (learn_hip m89/m91): A[m=lane&15][k=q*8+j],
// D[row=q*4+r][col=lane&15]; W[4F,F] row-major == gemm-BT B-frag layout.

#define NN 30000
#define DMAXX 16

typedef __bf16 bf16_t;
typedef __bf16 bf16x8 __attribute__((ext_vector_type(8)));
typedef float f32x4 __attribute__((ext_vector_type(4)));
typedef unsigned short u16x4 __attribute__((ext_vector_type(4)));

// persistent scratch (fully rewritten every call; no cross-call state reuse)
__device__ __align__(16) bf16_t g_hbuf[(size_t)NN * 256];    // layer-1 output h1
__device__ __align__(16) bf16_t g_xg1[(size_t)NN * 512];     // feat@Wih1^T + biases
__device__ __align__(16) bf16_t g_xg2[(size_t)NN * 1024];    // h1@Wih2^T + biases
__device__ __align__(16) bf16_t g_wbuf[753664];              // bf16 weight copies
__device__ int g_perm[NN];                                   // degree-sorted node ids

#define OFF_WIH1 0
#define OFF_WHH1 65536
#define OFF_WSELF1 131072
#define OFF_WNEIGH1 163840
#define OFF_WIH2 196608
#define OFF_WHH2 458752
#define OFF_WSELF2 720896
#define OFF_WNEIGH2 737280
#define W_TOTAL 753664

__global__ __launch_bounds__(256)
void cvt_weights(const float* __restrict__ s0, const float* __restrict__ s1,
                 const float* __restrict__ s2, const float* __restrict__ s3,
                 const float* __restrict__ s4, const float* __restrict__ s5,
                 const float* __restrict__ s6, const float* __restrict__ s7)
{
    int i = (blockIdx.x * 256 + threadIdx.x) * 4;
    if (i >= W_TOTAL) return;
    const float* src; int off;
    if      (i < OFF_WHH1)   { src = s0; off = OFF_WIH1; }
    else if (i < OFF_WSELF1) { src = s1; off = OFF_WHH1; }
    else if (i < OFF_WNEIGH1){ src = s2; off = OFF_WSELF1; }
    else if (i < OFF_WIH2)   { src = s3; off = OFF_WNEIGH1; }
    else if (i < OFF_WHH2)   { src = s4; off = OFF_WIH2; }
    else if (i < OFF_WSELF2) { src = s5; off = OFF_WHH2; }
    else if (i < OFF_WNEIGH2){ src = s6; off = OFF_WSELF2; }
    else                     { src = s7; off = OFF_WNEIGH2; }
    float4 v = *reinterpret_cast<const float4*>(src + (i - off));
    bf16_t o[4] __attribute__((aligned(8)));
    o[0] = (bf16_t)v.x; o[1] = (bf16_t)v.y; o[2] = (bf16_t)v.z; o[3] = (bf16_t)v.w;
    *reinterpret_cast<uint2*>(&g_wbuf[i]) = *reinterpret_cast<const uint2*>(o);
}

// counting sort of node ids by DESCENDING degree (LPT block scheduling).
__global__ __launch_bounds__(256)
void build_perm(const int* __restrict__ deg, int* __restrict__ perm)
{
    __shared__ int s_base[DMAXX + 1];
    const int tid = threadIdx.x;
    if (tid <= DMAXX) s_base[tid] = 0;
    __syncthreads();
    for (int i = tid; i < NN; i += 256) {
        int d = deg[i]; d = d < 0 ? 0 : (d > DMAXX ? DMAXX : d);
        atomicAdd(&s_base[d], 1);
    }
    __syncthreads();
    if (tid == 0) {
        int acc = 0;
        for (int d = DMAXX; d >= 0; --d) { int c = s_base[d]; s_base[d] = acc; acc += c; }
    }
    __syncthreads();
    for (int i = tid; i < NN; i += 256) {
        int d = deg[i]; d = d < 0 ? 0 : (d > DMAXX ? DMAXX : d);
        int p = atomicAdd(&s_base[d], 1);
        perm[p] = i;
    }
}

__device__ __forceinline__ float fsig(float x) { return 1.0f / (1.0f + __expf(-x)); }
__device__ __forceinline__ float ftanh(float x) { return 1.0f - 2.0f / (__expf(2.0f * x) + 1.0f); }
__device__ __forceinline__ float bf2f(unsigned short s) {
    union { unsigned u; float f; } v; v.u = ((unsigned)s) << 16; return v.f;
}

// stage a 64-row x-tile (linear rows, row-clamped) into LDS as bf16
template<int F, int LDA, int NT, bool XF32>
__device__ __forceinline__ void stage_tile(bf16_t* dst, const void* src, int row0, int tid)
{
    constexpr int UN = F / 8;          // 16B(bf16) units per row
    for (int e = tid; e < 64 * UN; e += NT) {
        int m = e / UN, sub = e - m * UN;
        int row = row0 + m; if (row >= NN) row = NN - 1;
        if constexpr (XF32) {
            const float* p = (const float*)src + (size_t)row * F + sub * 8;
            float4 f0 = reinterpret_cast<const float4*>(p)[0];
            float4 f1 = reinterpret_cast<const float4*>(p)[1];
            bf16_t t[8] __attribute__((aligned(16)));
            t[0]=(bf16_t)f0.x; t[1]=(bf16_t)f0.y; t[2]=(bf16_t)f0.z; t[3]=(bf16_t)f0.w;
            t[4]=(bf16_t)f1.x; t[5]=(bf16_t)f1.y; t[6]=(bf16_t)f1.z; t[7]=(bf16_t)f1.w;
            *reinterpret_cast<uint4*>(&dst[m * LDA + sub * 8]) = *reinterpret_cast<const uint4*>(t);
        } else {
            const bf16_t* p = (const bf16_t*)src + (size_t)row * F + sub * 8;
            *reinterpret_cast<uint4*>(&dst[m * LDA + sub * 8]) = *reinterpret_cast<const uint4*>(p);
        }
    }
}

// stage a 64-row x-tile with per-row node ids (from LDS array) into LDS
template<int F, int LDA, int NT, bool XF32>
__device__ __forceinline__ void stage_rows(bf16_t* dst, const void* src, const int* nodes, int tid)
{
    constexpr int UN = F / 8;
    for (int e = tid; e < 64 * UN; e += NT) {
        int m = e / UN, sub = e - m * UN;
        int row = nodes[m];
        if constexpr (XF32) {
            const float* p = (const float*)src + (size_t)row * F + sub * 8;
            float4 f0 = reinterpret_cast<const float4*>(p)[0];
            float4 f1 = reinterpret_cast<const float4*>(p)[1];
            bf16_t t[8] __attribute__((aligned(16)));
            t[0]=(bf16_t)f0.x; t[1]=(bf16_t)f0.y; t[2]=(bf16_t)f0.z; t[3]=(bf16_t)f0.w;
            t[4]=(bf16_t)f1.x; t[5]=(bf16_t)f1.y; t[6]=(bf16_t)f1.z; t[7]=(bf16_t)f1.w;
            *reinterpret_cast<uint4*>(&dst[m * LDA + sub * 8]) = *reinterpret_cast<const uint4*>(t);
        } else {
            const bf16_t* p = (const bf16_t*)src + (size_t)row * F + sub * 8;
            *reinterpret_cast<uint4*>(&dst[m * LDA + sub * 8]) = *reinterpret_cast<const uint4*>(p);
        }
    }
}

// xg[N, 4F] (gate-interleaved [c][g]) = x[N,F] @ W[4F,F]^T + b0 + b1
template<int F, int G, int NW, bool XF32>
__global__ __launch_bounds__(NW * 64, 2)
void xg_gemm(const void* __restrict__ xsrc_v, const bf16_t* __restrict__ W,
             const float* __restrict__ b0, const float* __restrict__ b1v,
             bf16_t* __restrict__ xg)
{
    constexpr int LDA = F + 8, KK = F / 32, NT = NW * 64;
    constexpr int CPW = G / NW;        // linear out-cols per wave
    constexpr int CT = CPW / 16;
    static_assert(CPW % 16 == 0 && F % 16 == 0, "");
    const int tid = threadIdx.x, wave = tid >> 6, lane = tid & 63;
    const int q = lane >> 4, m16 = lane & 15;
    const int row0 = blockIdx.x * 64;

    __shared__ __align__(16) bf16_t s_x[64 * LDA];
    stage_tile<F, LDA, NT, XF32>(s_x, xsrc_v, row0, tid);
    __syncthreads();

    #pragma unroll
    for (int ct = 0; ct < CT; ++ct) {
        const int lc0 = wave * CPW + ct * 16;   // linear col block (within one gate)
        const int g = lc0 / F, c0 = lc0 - g * F;
        const float bias = b0[lc0 + m16] + b1v[lc0 + m16];
        f32x4 acc[4];
        #pragma unroll
        for (int rt = 0; rt < 4; ++rt)
            #pragma unroll
            for (int r = 0; r < 4; ++r) acc[rt][r] = bias;
        #pragma unroll
        for (int kk = 0; kk < KK; ++kk) {
            const int ko = kk * 32 + q * 8;
            bf16x8 b = *reinterpret_cast<const bf16x8*>(W + (size_t)(lc0 + m16) * F + ko);
            #pragma unroll
            for (int rt = 0; rt < 4; ++rt) {
                bf16x8 a = *reinterpret_cast<const bf16x8*>(&s_x[(rt * 16 + m16) * LDA + ko]);
                acc[rt] = __builtin_amdgcn_mfma_f32_16x16x32_bf16(a, b, acc[rt], 0, 0, 0);
            }
        }
        #pragma unroll
        for (int rt = 0; rt < 4; ++rt)
            #pragma unroll
            for (int r = 0; r < 4; ++r) {
                int row = row0 + rt * 16 + q * 4 + r;
                if (row < NN)
                    xg[(size_t)row * G + (size_t)(c0 + m16) * 4 + g] = (bf16_t)acc[rt][r];
            }
    }
}

// LSTM recurrence over gathered neighbors + fused fc epilogue.
// Block b: nodes perm[b*64 .. b*64+63] (degree-sorted DESC), loops to
// tmax = max(deg in block). 16 waves = NWR row-groups x NWC col-waves
// (16 cols each). Each step runs NPASS sequential passes of 2 row-tiles;
// per-pass state is transient (no spill at the 128-reg 16-wave budget).
// gates = gather(xg) + h @ Whh^T ; out = x_self@Wself^T + h_fin@Wneigh^T + b
template<int F, int OUTF, bool RELU, bool XF32, typename OutT>
__global__ __launch_bounds__(1024, 4)
void sage_rec(const void* __restrict__ xself_v,
              const bf16_t* __restrict__ xg,
              const int* __restrict__ nbr_idx, const int* __restrict__ deg,
              const int* __restrict__ perm,
              const bf16_t* __restrict__ Whh,
              const bf16_t* __restrict__ Wself, const bf16_t* __restrict__ Wneigh,
              const float* __restrict__ bout, OutT* __restrict__ outp)
{
    constexpr int M = 64, LDA = F + 8, KK = F / 32, NW = 16, NT = 1024;
    constexpr int NWC = F / 16;            // col-waves, 16 cols each
    constexpr int NWR = NW / NWC;          // row-groups (1 for F=256, 2 for F=128)
    constexpr int RT = M / (16 * NWR);     // row-tiles per wave (4 or 2)
    constexpr int NPASS = RT / 2;          // 2 row-tiles per pass
    constexpr int G4 = 4 * F;
    static_assert(NWC * NWR == NW && RT % 2 == 0, "");
    const int tid = threadIdx.x, wave = tid >> 6, lane = tid & 63;
    const int q = lane >> 4, m16 = lane & 15;
    const int wc = wave % NWC, wr = wave / NWC;
    const int ROWB = wr * (RT * 16);       // this wave's row base in tile
    const int col = wc * 16 + m16;         // this lane's output column (per gate)
    const int slot0 = blockIdx.x * M;

    __shared__ __align__(16) bf16_t s_h[2][M * LDA];   // double-buffered h
    __shared__ int s_idx[M * DMAXX];
    __shared__ int s_deg[M];
    __shared__ int s_node[M];
    __shared__ int s_tmax;

    for (int i = tid; i < M; i += NT) {
        int slot = slot0 + i; if (slot >= NN) slot = NN - 1;
        int node = perm[slot];
        s_node[i] = node;
        s_deg[i] = deg[node];
    }
    __syncthreads();
    for (int i = tid; i < M * DMAXX; i += NT) {
        int node = s_node[i >> 4];
        int v = nbr_idx[node * DMAXX + (i & 15)];
        if (v < 0) v = 0; if (v >= NN) v = NN - 1;
        s_idx[i] = v;
    }
    for (int i = tid; i < M * LDA; i += NT) s_h[0][i] = (bf16_t)0.0f;
    if (tid == 0) {
        int mx = 1;
        for (int i = 0; i < M; ++i) { int d = s_deg[i]; mx = d > mx ? d : mx; }
        s_tmax = mx;
    }
    __syncthreads();
    const int tmax = s_tmax;   // uniform-degree blocks: ~= block's degree bucket

    // persistent cell state: one f32x4 per row-tile (named, never runtime-indexed)
    f32x4 c0, c1, c2, c3;
    #pragma unroll
    for (int r = 0; r < 4; ++r) { c0[r]=0.f; c1[r]=0.f; c2[r]=0.f; c3[r]=0.f; }

    // one pass: 2 row-tiles (rtb, rtb+1) x all 4 gates for this wave's 16 cols
    auto do_pass = [&](int rtb, f32x4& cA, f32x4& cB,
                       const bf16_t* cur, bf16_t* nxt, int t) {
        // gather gate-init (xg = x@Wih^T + biases), 8B/lane/row
        u16x4 u[2][4];
        #pragma unroll
        for (int j = 0; j < 2; ++j)
            #pragma unroll
            for (int r = 0; r < 4; ++r) {
                int row = s_idx[(ROWB + (rtb + j) * 16 + q * 4 + r) * DMAXX + t];
                u[j][r] = *reinterpret_cast<const u16x4*>(
                    xg + (size_t)row * G4 + (size_t)col * 4);
            }
        f32x4 acc[2][4];
        #pragma unroll
        for (int j = 0; j < 2; ++j)
            #pragma unroll
            for (int g = 0; g < 4; ++g)
                #pragma unroll
                for (int r = 0; r < 4; ++r) acc[j][g][r] = 0.0f;
        #pragma unroll
        for (int kk = 0; kk < KK; ++kk) {
            const int ko = kk * 32 + q * 8;
            bf16x8 ah0 = *reinterpret_cast<const bf16x8*>(
                &cur[(ROWB + rtb * 16 + m16) * LDA + ko]);
            bf16x8 ah1 = *reinterpret_cast<const bf16x8*>(
                &cur[(ROWB + (rtb + 1) * 16 + m16) * LDA + ko]);
            #pragma unroll
            for (int g = 0; g < 4; ++g) {
                bf16x8 bh = *reinterpret_cast<const bf16x8*>(
                    Whh + (size_t)(g * F + col) * F + ko);
                acc[0][g] = __builtin_amdgcn_mfma_f32_16x16x32_bf16(ah0, bh, acc[0][g], 0, 0, 0);
                acc[1][g] = __builtin_amdgcn_mfma_f32_16x16x32_bf16(ah1, bh, acc[1][g], 0, 0, 0);
            }
        }
        // pointwise LSTM update + masked store:
        //   t <  deg : write h_new (and update c)
        //   t == deg : copy frozen h from cur (this thread's t-1 write)
        //   t >  deg : skip -- nxt already holds the frozen value
        #pragma unroll
        for (int j = 0; j < 2; ++j) {
            f32x4& cc = j ? cB : cA;
            #pragma unroll
            for (int r = 0; r < 4; ++r) {
                int rowr = ROWB + (rtb + j) * 16 + q * 4 + r;
                float iv = fsig (acc[j][0][r] + bf2f(u[j][r].x));
                float fv = fsig (acc[j][1][r] + bf2f(u[j][r].y));
                float gv = ftanh(acc[j][2][r] + bf2f(u[j][r].z));
                float ov = fsig (acc[j][3][r] + bf2f(u[j][r].w));
                float cn = fv * cc[r] + iv * gv;
                float hv = ov * ftanh(cn);
                const int pos = rowr * LDA + col;
                int d = s_deg[rowr];
                if (t < d) {
                    cc[r] = cn;
                    nxt[pos] = (bf16_t)hv;
                } else if (t == d) {
                    reinterpret_cast<unsigned short*>(nxt)[pos] =
                        reinterpret_cast<const unsigned short*>(cur)[pos];
                }
            }
        }
    };

    #pragma unroll 1
    for (int t = 0; t < tmax; ++t) {
        const bf16_t* cur = s_h[t & 1];
        bf16_t* nxt = s_h[(t + 1) & 1];
        do_pass(0, c0, c1, cur, nxt, t);
        if constexpr (NPASS > 1) {
            __builtin_amdgcn_sched_barrier(0);   // keep passes sequential (reg pressure)
            do_pass(2, c2, c3, cur, nxt, t);
        }
        __syncthreads();   // nxt fully written; cur fully consumed
    }

    // final h is in s_h[tmax&1]; stage self-rows into the other buffer
    const int fb = tmax & 1;
    const bf16_t* hfin = s_h[fb];
    bf16_t* hstage = s_h[fb ^ 1];
    stage_rows<F, LDA, NT, XF32>(hstage, xself_v, s_node, tid);
    __syncthreads();

    // epilogue: out = x_self @ Wself^T + h_fin @ Wneigh^T + bout (+relu)
    constexpr int NCT = OUTF / 16;
    constexpr int TILES = NCT * 4;     // 4 row-tiles of the 64-node tile
    constexpr int TPW = TILES / NW;
    static_assert(TILES % NW == 0, "");
    #pragma unroll
    for (int tt = 0; tt < TPW; ++tt) {
        int tile = wave * TPW + tt;
        int ot = tile % NCT, rt = tile / NCT;
        f32x4 o;
        o[0] = 0.f; o[1] = 0.f; o[2] = 0.f; o[3] = 0.f;
        #pragma unroll
        for (int kk = 0; kk < KK; ++kk) {
            const int ko = kk * 32 + q * 8;
            bf16x8 axs = *reinterpret_cast<const bf16x8*>(&hstage[(rt * 16 + m16) * LDA + ko]);
            bf16x8 am  = *reinterpret_cast<const bf16x8*>(&hfin[(rt * 16 + m16) * LDA + ko]);
            bf16x8 bs = *reinterpret_cast<const bf16x8*>(Wself  + (size_t)(ot * 16 + m16) * F + ko);
            bf16x8 bn = *reinterpret_cast<const bf16x8*>(Wneigh + (size_t)(ot * 16 + m16) * F + ko);
            o = __builtin_amdgcn_mfma_f32_16x16x32_bf16(axs, bs, o, 0, 0, 0);
            o = __builtin_amdgcn_mfma_f32_16x16x32_bf16(am,  bn, o, 0, 0, 0);
        }
        int ocol = ot * 16 + m16;
        float bias = bout[ocol];
        #pragma unroll
        for (int r = 0; r < 4; ++r) {
            int node = s_node[rt * 16 + q * 4 + r];
            float v = o[r] + bias;
            if (RELU) v = fmaxf(v, 0.0f);
            outp[(size_t)node * OUTF + ocol] = (OutT)v;
        }
    }
}

extern "C" void kernel_launch(void* const* d_in, const int* in_sizes, int n_in,
                              void* d_out, int out_size, void* d_ws, size_t ws_size,
                              hipStream_t stream)
{
    const float* feat    = (const float*)d_in[0];
    const int*   nbr     = (const int*)d_in[1];
    const int*   degp    = (const int*)d_in[2];
    const float* Wih1    = (const float*)d_in[3];
    const float* Whh1    = (const float*)d_in[4];
    const float* bih1    = (const float*)d_in[5];
    const float* bhh1    = (const float*)d_in[6];
    const float* Wself1  = (const float*)d_in[7];
    const float* Wneigh1 = (const float*)d_in[8];
    const float* b1      = (const float*)d_in[9];
    const float* Wih2    = (const float*)d_in[10];
    const float* Whh2    = (const float*)d_in[11];
    const float* bih2    = (const float*)d_in[12];
    const float* bhh2    = (const float*)d_in[13];
    const float* Wself2  = (const float*)d_in[14];
    const float* Wneigh2 = (const float*)d_in[15];
    const float* b2      = (const float*)d_in[16];

    bf16_t *hglob, *wglob, *xg1, *xg2;
    int *permg;
    hipGetSymbolAddress((void**)&hglob, HIP_SYMBOL(g_hbuf));
    hipGetSymbolAddress((void**)&wglob, HIP_SYMBOL(g_wbuf));
    hipGetSymbolAddress((void**)&xg1,   HIP_SYMBOL(g_xg1));
    hipGetSymbolAddress((void**)&xg2,   HIP_SYMBOL(g_xg2));
    hipGetSymbolAddress((void**)&permg, HIP_SYMBOL(g_perm));

    cvt_weights<<<W_TOTAL / 4 / 256, 256, 0, stream>>>(
        Wih1, Whh1, Wself1, Wneigh1, Wih2, Whh2, Wself2, Wneigh2);

    build_perm<<<1, 256, 0, stream>>>(degp, permg);

    const int grid = (NN + 63) / 64;   // 469 WGs

    xg_gemm<128, 512, 8, true><<<grid, 512, 0, stream>>>(
        feat, wglob + OFF_WIH1, bih1, bhh1, xg1);

    sage_rec<128, 256, true, true, bf16_t><<<grid, 1024, 0, stream>>>(
        feat, xg1, nbr, degp, permg, wglob + OFF_WHH1,
        wglob + OFF_WSELF1, wglob + OFF_WNEIGH1, b1, hglob);

    xg_gemm<256, 1024, 8, false><<<grid, 512, 0, stream>>>(
        hglob, wglob + OFF_WIH2, bih2, bhh2, xg2);

    sage_rec<256, 64, false, false, float><<<grid, 1024, 0, stream>>>(
        hglob, xg2, nbr, degp, permg, wglob + OFF_WHH2,
        wglob + OFF_WSELF2, wglob + OFF_WNEIGH2, b2, (float*)d_out);
}